// Round 8
// baseline (141.267 us; speedup 1.0000x reference)
//
#include <hip/hip_runtime.h>

// Legendre2 via split-precision MFMA, v8: level-streamed A-table.
// Prep kernel materializes per-level 16 KB fragment blocks (f16 hi 8KB || lo
// 8KB) of A (=coef*Tnorm) and bf16 hi/lo fragment table of C into d_ws.
// Main kernel (512 thr, 8 waves, 512 blocks, 128 rows/wave): LDS = 2x16 KB
// level double-buffer + 8 KB C = 40960 B (< 64 KiB default path -- R2/R7
// evidence says the >64K dynamic-LDS opt-in caps residency at 1 block/CU).
// While level g computes from buf[g&1], level g+2 is loaded global->regs
// (8 VGPRs, one full compute level of latency cover) and level g+1 (loaded
// last level) is ds-written to the other buffer after a barrier.
// Epilogue transpose scratch reuses the idle buf1 region (parity: buf1 is
// always free during epilogues). Numerics identical to R2-R7.
// N=524288, D=64, K=64, O=32, DEGREE=6.

typedef _Float16 f16x8 __attribute__((ext_vector_type(8)));
typedef short    s16x8 __attribute__((ext_vector_type(8)));
typedef float    f32x4 __attribute__((ext_vector_type(4)));

#define NN      524288
#define BLOCKS  512
#define THREADS 512
#define NWAVES  8
#define ROWS_PER_WAVE 128               // 512 blocks * 8 waves * 128 = N
#define NITER   4                       // 4 x 32-row tiles per wave
#define GMAX    (NITER * 6 - 1)         // last global level index

// d_ws byte layout (prep output): level L at L*16384 = [hi 8KB][lo 8KB]
#define WS_CF   98304                   // 8 frags * 1 KB (bf16 h/l of C)
#define WS_TOTAL (98304 + 8192)

// main-kernel LDS byte offsets (total 40960 B)
#define BUF0_OFF 0
#define BUF1_OFF 16384
#define CF_OFF   32768
#define SMEM_BYTES 40960

__device__ __forceinline__ unsigned short f2bf(float x) {
    unsigned u = __builtin_bit_cast(unsigned, x);
    return (unsigned short)((u + 0x7FFFu + ((u >> 16) & 1u)) >> 16);
}

// ---------------------------------------------------------------------------
// prep: build fragment tables in d_ws
// ---------------------------------------------------------------------------
__global__ __launch_bounds__(512) void leg_prep(
    const float* __restrict__ T, const float* __restrict__ Cm,
    char* __restrict__ ws)
{
    __shared__ float scale_s[384];
    const int tid = (int)threadIdx.x;

    if (tid < 384) {
        const int mat = tid >> 6, kc = tid & 63;
        const float4* tr = (const float4*)(T + (size_t)((mat << 6) + kc) * 64);
        float s = 0.f;
        #pragma unroll
        for (int q = 0; q < 16; ++q) { float4 v = tr[q]; s += v.x + v.y + v.z + v.w; }
        float sc;
        if (mat == 0) sc = 1.f;
        else { const float fi = (float)(mat + 1); sc = (2.f * fi - 1.f) / fi / s; }
        scale_s[tid] = sc;
    }
    __syncthreads();

    // A fragments: level `mat`, frag(s,f): lane l supplies
    // A[col=(l&15)+16f][32s+(l>>4)*8+j] * scale, j=0..7.
    for (int g = tid; g < 3072; g += 512) {
        const int mat = g >> 9;
        const int s   = (g >> 8) & 1;
        const int f   = (g >> 6) & 3;
        const int l   = g & 63;
        const int kc  = (l & 15) + (f << 4);
        const int d0  = ((l >> 4) << 3) + (s << 5);
        const float sc = scale_s[(mat << 6) + kc];
        const float* src = T + (size_t)((mat << 6) + kc) * 64 + d0;
        const float4 v0 = *(const float4*)(src);
        const float4 v1 = *(const float4*)(src + 4);
        const float vv[8] = {v0.x, v0.y, v0.z, v0.w, v1.x, v1.y, v1.z, v1.w};
        f16x8 hi, lo;
        #pragma unroll
        for (int j = 0; j < 8; ++j) {
            const float x = vv[j] * sc;
            const _Float16 h = (_Float16)x;
            hi[j] = h;
            lo[j] = (_Float16)(x - (float)h);
        }
        char* lvlbase = ws + mat * 16384;
        const int fr = (s << 2) + f;                   // 0..7 within level
        *(f16x8*)(lvlbase + fr * 1024 + l * 16) = hi;
        *(f16x8*)(lvlbase + 8192 + fr * 1024 + l * 16) = lo;
    }

    // C fragments (bf16 hi/lo): frag(hl,s,fo), lane l supplies
    // C2[k=32s+(l>>4)*8+j][o=(l&15)+16fo] = C[o][k].
    {
        const int hl = (tid >> 8) & 1;
        const int s  = (tid >> 7) & 1;
        const int fo = (tid >> 6) & 1;
        const int l  = tid & 63;
        const int o  = (l & 15) + (fo << 4);
        const int k0 = ((l >> 4) << 3) + (s << 5);
        const float* src = Cm + (size_t)o * 64 + k0;
        const float4 v0 = *(const float4*)src;
        const float4 v1 = *(const float4*)(src + 4);
        const float vv[8] = {v0.x, v0.y, v0.z, v0.w, v1.x, v1.y, v1.z, v1.w};
        s16x8 fr;
        #pragma unroll
        for (int j = 0; j < 8; ++j) {
            const float x = vv[j];
            const unsigned short h = f2bf(x);
            if (hl) {
                const float hf = __builtin_bit_cast(float, (unsigned)h << 16);
                fr[j] = (short)f2bf(x - hf);
            } else {
                fr[j] = (short)h;
            }
        }
        *(s16x8*)(ws + WS_CF + ((((hl << 1) + s) << 1) + fo) * 1024 + l * 16) = fr;
    }
}

// ---------------------------------------------------------------------------
// main
// ---------------------------------------------------------------------------
__global__ __launch_bounds__(THREADS) void leg_mfma(
    const float* __restrict__ z, const char* __restrict__ ws,
    const float* __restrict__ beta, float* __restrict__ out)
{
    extern __shared__ char smem[];
    const int tid  = (int)threadIdx.x;
    const int lane = tid & 63;
    const int wv   = tid >> 6;
    const int lrow = lane & 15;          // row (A-op) / col (C/D) index
    const int lhi  = lane >> 4;          // 0..3

    struct Stg { f16x8 a, b; };
    auto load_lvl = [&](int lvl) -> Stg {
        const char* src = ws + lvl * 16384;
        Stg r;
        r.a = *(const f16x8*)(src + tid * 16);
        r.b = *(const f16x8*)(src + 8192 + tid * 16);
        return r;
    };
    auto write_buf = [&](char* buf, const Stg& r) {
        *(f16x8*)(buf + tid * 16) = r.a;               // lane-stride 16B: conflict-free
        *(f16x8*)(buf + 8192 + tid * 16) = r.b;
    };
    auto bufp = [&](int g) -> char* {
        return smem + ((g & 1) ? BUF1_OFF : BUF0_OFF);
    };

    // ---------------- prologue: stage lvl0 -> buf0, lvl1 -> regs, C ----------
    Stg rg = load_lvl(0);
    write_buf(smem + BUF0_OFF, rg);                    // compiler waits vmcnt
    rg = load_lvl(1);
    {
        // C frags: 8 KB, one f16x8 per thread
        *(f16x8*)(smem + CF_OFF + tid * 16) = *(const f16x8*)(ws + WS_CF + tid * 16);
    }
    __syncthreads();

    const int    gw      = blockIdx.x * NWAVES + wv;
    const size_t rowbase = (size_t)gw * ROWS_PER_WAVE;
    float* scr = (float*)(smem + BUF1_OFF) + wv * 512; // 2 KB/wave, buf1 reuse

    const float beta0 = beta[lrow];
    const float beta1 = beta[16 + lrow];

    f16x8 zh[2][2], zl[2][2];

    // barrier + stage rotation after computing level g; nlvl = (g+2)%6 const
    auto advance = [&](int g, int nlvl) {
        __syncthreads();                               // all done compute(g)
        if (g + 1 <= GMAX) write_buf(bufp(g + 1), rg);
        __syncthreads();                               // writes visible
        if (g + 2 <= GMAX) rg = load_lvl(nlvl);        // in flight for a level
    };

    // one Legendre level from buf frags: PT := W * PC - b * PT
    auto leg_step = [&](const char* buf, float b, f32x4 (&PC)[2][4], f32x4 (&PT)[2][4]) {
        #pragma unroll
        for (int f = 0; f < 4; ++f) {
            const f16x8 bh0 = *(const f16x8*)(buf + f * 1024 + lane * 16);
            const f16x8 bl0 = *(const f16x8*)(buf + 8192 + f * 1024 + lane * 16);
            const f16x8 bh1 = *(const f16x8*)(buf + (4 + f) * 1024 + lane * 16);
            const f16x8 bl1 = *(const f16x8*)(buf + 8192 + (4 + f) * 1024 + lane * 16);
            #pragma unroll
            for (int t = 0; t < 2; ++t) {
                f32x4 a = {0.f, 0.f, 0.f, 0.f};
                a = __builtin_amdgcn_mfma_f32_16x16x32_f16(zh[t][0], bh0, a, 0, 0, 0);
                a = __builtin_amdgcn_mfma_f32_16x16x32_f16(zl[t][0], bh0, a, 0, 0, 0);
                a = __builtin_amdgcn_mfma_f32_16x16x32_f16(zh[t][0], bl0, a, 0, 0, 0);
                a = __builtin_amdgcn_mfma_f32_16x16x32_f16(zh[t][1], bh1, a, 0, 0, 0);
                a = __builtin_amdgcn_mfma_f32_16x16x32_f16(zl[t][1], bh1, a, 0, 0, 0);
                a = __builtin_amdgcn_mfma_f32_16x16x32_f16(zh[t][1], bl1, a, 0, 0, 0);
                #pragma unroll
                for (int r = 0; r < 4; ++r)
                    PT[t][f][r] = a[r] * PC[t][f][r] - b * PT[t][f][r];
            }
        }
    };

    for (int it = 0; it < NITER; ++it) {
        const int g0 = it * 6;

        // load + convert z for this 32-row tile
        #pragma unroll
        for (int t = 0; t < 2; ++t)
            #pragma unroll
            for (int s = 0; s < 2; ++s) {
                const float* p = z + (rowbase + (size_t)it * 32 + t * 16 + lrow) * 64
                                   + (s << 5) + (lhi << 3);
                const float4 q0 = *(const float4*)(p);
                const float4 q1 = *(const float4*)(p + 4);
                const float vv[8] = {q0.x, q0.y, q0.z, q0.w, q1.x, q1.y, q1.z, q1.w};
                #pragma unroll
                for (int j = 0; j < 8; ++j) {
                    const _Float16 h = (_Float16)vv[j];
                    zh[t][s][j] = h;
                    zl[t][s][j] = (_Float16)(vv[j] - (float)h);
                }
            }

        f32x4 pA[2][4], pB[2][4];
        // level g0: mat0 -> pA (P1)
        {
            const char* buf = bufp(g0);
            #pragma unroll
            for (int f = 0; f < 4; ++f) {
                const f16x8 bh0 = *(const f16x8*)(buf + f * 1024 + lane * 16);
                const f16x8 bl0 = *(const f16x8*)(buf + 8192 + f * 1024 + lane * 16);
                const f16x8 bh1 = *(const f16x8*)(buf + (4 + f) * 1024 + lane * 16);
                const f16x8 bl1 = *(const f16x8*)(buf + 8192 + (4 + f) * 1024 + lane * 16);
                #pragma unroll
                for (int t = 0; t < 2; ++t) {
                    f32x4 a = {0.f, 0.f, 0.f, 0.f};
                    a = __builtin_amdgcn_mfma_f32_16x16x32_f16(zh[t][0], bh0, a, 0, 0, 0);
                    a = __builtin_amdgcn_mfma_f32_16x16x32_f16(zl[t][0], bh0, a, 0, 0, 0);
                    a = __builtin_amdgcn_mfma_f32_16x16x32_f16(zh[t][0], bl0, a, 0, 0, 0);
                    a = __builtin_amdgcn_mfma_f32_16x16x32_f16(zh[t][1], bh1, a, 0, 0, 0);
                    a = __builtin_amdgcn_mfma_f32_16x16x32_f16(zl[t][1], bh1, a, 0, 0, 0);
                    a = __builtin_amdgcn_mfma_f32_16x16x32_f16(zh[t][1], bl1, a, 0, 0, 0);
                    pA[t][f] = a;
                }
            }
        }
        advance(g0, 2);
        // level g0+1: mat1 -> pB = W2*pA - 0.5 (P2; P0 = ones)
        {
            const char* buf = bufp(g0 + 1);
            #pragma unroll
            for (int f = 0; f < 4; ++f) {
                const f16x8 bh0 = *(const f16x8*)(buf + f * 1024 + lane * 16);
                const f16x8 bl0 = *(const f16x8*)(buf + 8192 + f * 1024 + lane * 16);
                const f16x8 bh1 = *(const f16x8*)(buf + (4 + f) * 1024 + lane * 16);
                const f16x8 bl1 = *(const f16x8*)(buf + 8192 + (4 + f) * 1024 + lane * 16);
                #pragma unroll
                for (int t = 0; t < 2; ++t) {
                    f32x4 a = {0.f, 0.f, 0.f, 0.f};
                    a = __builtin_amdgcn_mfma_f32_16x16x32_f16(zh[t][0], bh0, a, 0, 0, 0);
                    a = __builtin_amdgcn_mfma_f32_16x16x32_f16(zl[t][0], bh0, a, 0, 0, 0);
                    a = __builtin_amdgcn_mfma_f32_16x16x32_f16(zh[t][0], bl0, a, 0, 0, 0);
                    a = __builtin_amdgcn_mfma_f32_16x16x32_f16(zh[t][1], bh1, a, 0, 0, 0);
                    a = __builtin_amdgcn_mfma_f32_16x16x32_f16(zl[t][1], bh1, a, 0, 0, 0);
                    a = __builtin_amdgcn_mfma_f32_16x16x32_f16(zh[t][1], bl1, a, 0, 0, 0);
                    #pragma unroll
                    for (int r = 0; r < 4; ++r)
                        pB[t][f][r] = a[r] * pA[t][f][r] - 0.5f;
                }
            }
        }
        advance(g0 + 1, 3);
        leg_step(bufp(g0 + 2), 2.f / 3.f, pB, pA);  advance(g0 + 2, 4);  // P3
        leg_step(bufp(g0 + 3), 3.f / 4.f, pA, pB);  advance(g0 + 3, 5);  // P4
        leg_step(bufp(g0 + 4), 4.f / 5.f, pB, pA);  advance(g0 + 4, 0);  // P5
        leg_step(bufp(g0 + 5), 5.f / 6.f, pA, pB);  advance(g0 + 5, 1);  // P6

        // ---------------- epilogue: out = P6 @ C^T + beta --------------------
        // (buf1 region is free here every iter: levels g0+6.. use buf0 first,
        //  and buf1 is only rewritten after the next compute's barrier)
        #pragma unroll
        for (int t = 0; t < 2; ++t) {
            s16x8 p6h[2], p6l[2];
            #pragma unroll
            for (int s = 0; s < 2; ++s) {
                #pragma unroll
                for (int f_ = 0; f_ < 2; ++f_) {
                    const int f    = 2 * s + f_;
                    const int colp = (f_ << 4) + lrow;
                    #pragma unroll
                    for (int r = 0; r < 4; ++r) {
                        const int row = lhi * 4 + r;
                        const int g4  = ((colp >> 2) ^ row) & 7;
                        scr[row * 32 + g4 * 4 + (colp & 3)] = pB[t][f][r];
                    }
                }
                float vv[8];
                #pragma unroll
                for (int jg = 0; jg < 2; ++jg) {
                    const int g4r = (((lhi << 1) + jg) ^ lrow) & 7;
                    const float4 q = *(const float4*)(scr + lrow * 32 + g4r * 4);
                    vv[jg * 4 + 0] = q.x; vv[jg * 4 + 1] = q.y;
                    vv[jg * 4 + 2] = q.z; vv[jg * 4 + 3] = q.w;
                }
                #pragma unroll
                for (int j = 0; j < 8; ++j) {
                    const unsigned short h = f2bf(vv[j]);
                    const float hf = __builtin_bit_cast(float, (unsigned)h << 16);
                    p6h[s][j] = (short)h;
                    p6l[s][j] = (short)f2bf(vv[j] - hf);
                }
            }
            #pragma unroll
            for (int fo = 0; fo < 2; ++fo) {
                const s16x8 ch0 = *(const s16x8*)(smem + CF_OFF + ((0 << 1) + fo) * 1024 + lane * 16);
                const s16x8 ch1 = *(const s16x8*)(smem + CF_OFF + ((1 << 1) + fo) * 1024 + lane * 16);
                const s16x8 cl0 = *(const s16x8*)(smem + CF_OFF + ((2 << 1) + fo) * 1024 + lane * 16);
                const s16x8 cl1 = *(const s16x8*)(smem + CF_OFF + ((3 << 1) + fo) * 1024 + lane * 16);
                f32x4 o = {0.f, 0.f, 0.f, 0.f};
                o = __builtin_amdgcn_mfma_f32_16x16x32_bf16(p6h[0], ch0, o, 0, 0, 0);
                o = __builtin_amdgcn_mfma_f32_16x16x32_bf16(p6l[0], ch0, o, 0, 0, 0);
                o = __builtin_amdgcn_mfma_f32_16x16x32_bf16(p6h[0], cl0, o, 0, 0, 0);
                o = __builtin_amdgcn_mfma_f32_16x16x32_bf16(p6h[1], ch1, o, 0, 0, 0);
                o = __builtin_amdgcn_mfma_f32_16x16x32_bf16(p6l[1], ch1, o, 0, 0, 0);
                o = __builtin_amdgcn_mfma_f32_16x16x32_bf16(p6h[1], cl1, o, 0, 0, 0);
                const float bb = fo ? beta1 : beta0;
                const size_t r0 = rowbase + (size_t)it * 32 + t * 16 + lhi * 4;
                #pragma unroll
                for (int r = 0; r < 4; ++r)
                    out[(r0 + r) * 32 + (fo << 4) + lrow] = o[r] + bb;
            }
        }
    }
}

extern "C" void kernel_launch(void* const* d_in, const int* in_sizes, int n_in,
                              void* d_out, int out_size, void* d_ws, size_t ws_size,
                              hipStream_t stream) {
    const float* z    = (const float*)d_in[0];
    const float* T    = (const float*)d_in[1];
    const float* C    = (const float*)d_in[2];
    const float* beta = (const float*)d_in[3];
    float* out = (float*)d_out;
    (void)in_sizes; (void)n_in; (void)out_size; (void)ws_size;

    char* ws = (char*)d_ws;              // needs WS_TOTAL = 104 KB

    leg_prep<<<1, 512, 0, stream>>>(T, C, ws);
    // NOTE: no hipFuncSetAttribute -- SMEM_BYTES < 64 KiB default path.
    leg_mfma<<<BLOCKS, THREADS, SMEM_BYTES, stream>>>(z, ws, beta, out);
}

// Round 9
// 93.454 us; speedup vs baseline: 1.5116x; 1.5116x over previous
//
#include <hip/hip_runtime.h>

// Legendre2 via split-precision MFMA, v9: 2-tile B-frag sharing for ILP.
// Full A-table (96 KB, 6 levels x [hi 8K | lo 8K]) + C (8 KB) staged once in
// LDS; NO barriers in the main loop (R8 lesson: per-level barriers serialize).
// Each wave processes 64 rows = TWO 32-row tiles per iter, loading each
// level's B-fragments ONCE and feeding both tiles: halves LDS reads per row,
// doubles per-wave MFMA chain count (16 independent chains/level).
// Register budget: amdgpu_waves_per_eu(2) -> 256-reg tier (we are pinned at
// 2 waves/SIMD by the 120 KB LDS anyway; use the whole file).
// W_i = Z @ A_i^T as f16 hi/lo 3-term MFMA (f32 accum), elementwise Legendre
// fold in f32 regs, epilogue P6 @ C^T + beta as bf16 hi/lo 3-term MFMA.
// N=524288, D=64, K=64, O=32, DEGREE=6.

typedef _Float16 f16x8 __attribute__((ext_vector_type(8)));
typedef short    s16x8 __attribute__((ext_vector_type(8)));
typedef float    f32x4 __attribute__((ext_vector_type(4)));

#define NN      524288
#define BLOCKS  256
#define THREADS 512
#define NWAVES  8
#define ROWS_PER_WAVE 256               // 256 blocks * 8 waves * 256 = N
#define NITER   4                       // 4 x 64-row (2-tile) passes per wave

// d_ws byte layout (prep output): level L at L*16384 = [hi 8KB][lo 8KB]
#define WS_CF   98304                   // 8 frags * 1 KB (bf16 h/l of C)
#define WS_TOTAL 106496

// main-kernel LDS byte offsets
#define A_OFF   0                       // 96 KB (6 levels)
#define CF_OFF  98304                   // 8 KB
#define SCR_OFF 106496                  // 8 waves * 2 KB transpose scratch
#define SMEM_BYTES (SCR_OFF + NWAVES * 2048)   // 122880 B

__device__ __forceinline__ unsigned short f2bf(float x) {
    unsigned u = __builtin_bit_cast(unsigned, x);
    return (unsigned short)((u + 0x7FFFu + ((u >> 16) & 1u)) >> 16);
}

// ---------------------------------------------------------------------------
// prep: build fragment tables in d_ws (unchanged from v8)
// ---------------------------------------------------------------------------
__global__ __launch_bounds__(512) void leg_prep(
    const float* __restrict__ T, const float* __restrict__ Cm,
    char* __restrict__ ws)
{
    __shared__ float scale_s[384];
    const int tid = (int)threadIdx.x;

    if (tid < 384) {
        const int mat = tid >> 6, kc = tid & 63;
        const float4* tr = (const float4*)(T + (size_t)((mat << 6) + kc) * 64);
        float s = 0.f;
        #pragma unroll
        for (int q = 0; q < 16; ++q) { float4 v = tr[q]; s += v.x + v.y + v.z + v.w; }
        float sc;
        if (mat == 0) sc = 1.f;
        else { const float fi = (float)(mat + 1); sc = (2.f * fi - 1.f) / fi / s; }
        scale_s[tid] = sc;
    }
    __syncthreads();

    // A fragments: level `mat`, frag(s,f): lane l supplies
    // A[col=(l&15)+16f][32s+(l>>4)*8+j] * scale, j=0..7.
    for (int g = tid; g < 3072; g += 512) {
        const int mat = g >> 9;
        const int s   = (g >> 8) & 1;
        const int f   = (g >> 6) & 3;
        const int l   = g & 63;
        const int kc  = (l & 15) + (f << 4);
        const int d0  = ((l >> 4) << 3) + (s << 5);
        const float sc = scale_s[(mat << 6) + kc];
        const float* src = T + (size_t)((mat << 6) + kc) * 64 + d0;
        const float4 v0 = *(const float4*)(src);
        const float4 v1 = *(const float4*)(src + 4);
        const float vv[8] = {v0.x, v0.y, v0.z, v0.w, v1.x, v1.y, v1.z, v1.w};
        f16x8 hi, lo;
        #pragma unroll
        for (int j = 0; j < 8; ++j) {
            const float x = vv[j] * sc;
            const _Float16 h = (_Float16)x;
            hi[j] = h;
            lo[j] = (_Float16)(x - (float)h);
        }
        char* lvlbase = ws + mat * 16384;
        const int fr = (s << 2) + f;                   // 0..7 within level
        *(f16x8*)(lvlbase + fr * 1024 + l * 16) = hi;
        *(f16x8*)(lvlbase + 8192 + fr * 1024 + l * 16) = lo;
    }

    // C fragments (bf16 hi/lo): frag(hl,s,fo), lane l supplies
    // C2[k=32s+(l>>4)*8+j][o=(l&15)+16fo] = C[o][k].
    {
        const int hl = (tid >> 8) & 1;
        const int s  = (tid >> 7) & 1;
        const int fo = (tid >> 6) & 1;
        const int l  = tid & 63;
        const int o  = (l & 15) + (fo << 4);
        const int k0 = ((l >> 4) << 3) + (s << 5);
        const float* src = Cm + (size_t)o * 64 + k0;
        const float4 v0 = *(const float4*)src;
        const float4 v1 = *(const float4*)(src + 4);
        const float vv[8] = {v0.x, v0.y, v0.z, v0.w, v1.x, v1.y, v1.z, v1.w};
        s16x8 fr;
        #pragma unroll
        for (int j = 0; j < 8; ++j) {
            const float x = vv[j];
            const unsigned short h = f2bf(x);
            if (hl) {
                const float hf = __builtin_bit_cast(float, (unsigned)h << 16);
                fr[j] = (short)f2bf(x - hf);
            } else {
                fr[j] = (short)h;
            }
        }
        *(s16x8*)(ws + WS_CF + ((((hl << 1) + s) << 1) + fo) * 1024 + l * 16) = fr;
    }
}

// ---------------------------------------------------------------------------
// main
// ---------------------------------------------------------------------------
__global__ __launch_bounds__(THREADS)
__attribute__((amdgpu_waves_per_eu(2)))
void leg_mfma(
    const float* __restrict__ z, const char* __restrict__ ws,
    const float* __restrict__ beta, float* __restrict__ out)
{
    extern __shared__ char smem[];
    const int tid  = (int)threadIdx.x;
    const int lane = tid & 63;
    const int wv   = tid >> 6;
    const int lrow = lane & 15;          // row (A-op) / col (C/D) index
    const int lhi  = lane >> 4;          // 0..3

    // stage A levels + C: one linear 104 KB copy (ws layout matches LDS)
    for (int i = tid; i < WS_TOTAL / 16; i += THREADS)
        *(f16x8*)(smem + i * 16) = *(const f16x8*)(ws + i * 16);
    __syncthreads();

    const int    gw      = blockIdx.x * NWAVES + wv;
    const size_t rowbase = (size_t)gw * ROWS_PER_WAVE;
    float* scr = (float*)(smem + SCR_OFF) + wv * 512;  // 16 rows x 32 f32

    const float beta0 = beta[lrow];
    const float beta1 = beta[16 + lrow];

    f16x8 zh[2][2][2], zl[2][2][2];      // [tile u][t][s]

    // one Legendre level, B-frags loaded ONCE, applied to both tiles:
    // PT := W * PC - b * PT
    auto leg_level = [&](int lvl, float b,
                         f32x4 (&PC)[2][2][4], f32x4 (&PT)[2][2][4]) {
        const char* buf = smem + A_OFF + lvl * 16384;
        #pragma unroll
        for (int f = 0; f < 4; ++f) {
            const f16x8 bh0 = *(const f16x8*)(buf + f * 1024 + lane * 16);
            const f16x8 bl0 = *(const f16x8*)(buf + 8192 + f * 1024 + lane * 16);
            const f16x8 bh1 = *(const f16x8*)(buf + (4 + f) * 1024 + lane * 16);
            const f16x8 bl1 = *(const f16x8*)(buf + 8192 + (4 + f) * 1024 + lane * 16);
            #pragma unroll
            for (int u = 0; u < 2; ++u)
                #pragma unroll
                for (int t = 0; t < 2; ++t) {
                    f32x4 a = {0.f, 0.f, 0.f, 0.f};
                    a = __builtin_amdgcn_mfma_f32_16x16x32_f16(zh[u][t][0], bh0, a, 0, 0, 0);
                    a = __builtin_amdgcn_mfma_f32_16x16x32_f16(zl[u][t][0], bh0, a, 0, 0, 0);
                    a = __builtin_amdgcn_mfma_f32_16x16x32_f16(zh[u][t][0], bl0, a, 0, 0, 0);
                    a = __builtin_amdgcn_mfma_f32_16x16x32_f16(zh[u][t][1], bh1, a, 0, 0, 0);
                    a = __builtin_amdgcn_mfma_f32_16x16x32_f16(zl[u][t][1], bh1, a, 0, 0, 0);
                    a = __builtin_amdgcn_mfma_f32_16x16x32_f16(zh[u][t][1], bl1, a, 0, 0, 0);
                    #pragma unroll
                    for (int r = 0; r < 4; ++r)
                        PT[u][t][f][r] = a[r] * PC[u][t][f][r] - b * PT[u][t][f][r];
                }
        }
    };

    for (int it = 0; it < NITER; ++it) {
        // load + convert z for both tiles (tile-sequential to cap transients)
        #pragma unroll
        for (int u = 0; u < 2; ++u)
            #pragma unroll
            for (int t = 0; t < 2; ++t)
                #pragma unroll
                for (int s = 0; s < 2; ++s) {
                    const float* p = z + (rowbase + (size_t)it * 64 + u * 32 + t * 16 + lrow) * 64
                                       + (s << 5) + (lhi << 3);
                    const float4 q0 = *(const float4*)(p);
                    const float4 q1 = *(const float4*)(p + 4);
                    const float vv[8] = {q0.x, q0.y, q0.z, q0.w, q1.x, q1.y, q1.z, q1.w};
                    #pragma unroll
                    for (int j = 0; j < 8; ++j) {
                        const _Float16 h = (_Float16)vv[j];
                        zh[u][t][s][j] = h;
                        zl[u][t][s][j] = (_Float16)(vv[j] - (float)h);
                    }
                }

        // Legendre chain: pA = P1, pB = P2, then ping-pong; P6 ends in pB
        f32x4 pA[2][2][4], pB[2][2][4];
        // level 0 -> pA (P1)
        {
            const char* buf = smem + A_OFF;
            #pragma unroll
            for (int f = 0; f < 4; ++f) {
                const f16x8 bh0 = *(const f16x8*)(buf + f * 1024 + lane * 16);
                const f16x8 bl0 = *(const f16x8*)(buf + 8192 + f * 1024 + lane * 16);
                const f16x8 bh1 = *(const f16x8*)(buf + (4 + f) * 1024 + lane * 16);
                const f16x8 bl1 = *(const f16x8*)(buf + 8192 + (4 + f) * 1024 + lane * 16);
                #pragma unroll
                for (int u = 0; u < 2; ++u)
                    #pragma unroll
                    for (int t = 0; t < 2; ++t) {
                        f32x4 a = {0.f, 0.f, 0.f, 0.f};
                        a = __builtin_amdgcn_mfma_f32_16x16x32_f16(zh[u][t][0], bh0, a, 0, 0, 0);
                        a = __builtin_amdgcn_mfma_f32_16x16x32_f16(zl[u][t][0], bh0, a, 0, 0, 0);
                        a = __builtin_amdgcn_mfma_f32_16x16x32_f16(zh[u][t][0], bl0, a, 0, 0, 0);
                        a = __builtin_amdgcn_mfma_f32_16x16x32_f16(zh[u][t][1], bh1, a, 0, 0, 0);
                        a = __builtin_amdgcn_mfma_f32_16x16x32_f16(zl[u][t][1], bh1, a, 0, 0, 0);
                        a = __builtin_amdgcn_mfma_f32_16x16x32_f16(zh[u][t][1], bl1, a, 0, 0, 0);
                        pA[u][t][f] = a;
                    }
            }
        }
        // level 1 -> pB = W2*pA - 0.5 (P2; P0 = ones)
        {
            const char* buf = smem + A_OFF + 16384;
            #pragma unroll
            for (int f = 0; f < 4; ++f) {
                const f16x8 bh0 = *(const f16x8*)(buf + f * 1024 + lane * 16);
                const f16x8 bl0 = *(const f16x8*)(buf + 8192 + f * 1024 + lane * 16);
                const f16x8 bh1 = *(const f16x8*)(buf + (4 + f) * 1024 + lane * 16);
                const f16x8 bl1 = *(const f16x8*)(buf + 8192 + (4 + f) * 1024 + lane * 16);
                #pragma unroll
                for (int u = 0; u < 2; ++u)
                    #pragma unroll
                    for (int t = 0; t < 2; ++t) {
                        f32x4 a = {0.f, 0.f, 0.f, 0.f};
                        a = __builtin_amdgcn_mfma_f32_16x16x32_f16(zh[u][t][0], bh0, a, 0, 0, 0);
                        a = __builtin_amdgcn_mfma_f32_16x16x32_f16(zl[u][t][0], bh0, a, 0, 0, 0);
                        a = __builtin_amdgcn_mfma_f32_16x16x32_f16(zh[u][t][0], bl0, a, 0, 0, 0);
                        a = __builtin_amdgcn_mfma_f32_16x16x32_f16(zh[u][t][1], bh1, a, 0, 0, 0);
                        a = __builtin_amdgcn_mfma_f32_16x16x32_f16(zl[u][t][1], bh1, a, 0, 0, 0);
                        a = __builtin_amdgcn_mfma_f32_16x16x32_f16(zh[u][t][1], bl1, a, 0, 0, 0);
                        #pragma unroll
                        for (int r = 0; r < 4; ++r)
                            pB[u][t][f][r] = a[r] * pA[u][t][f][r] - 0.5f;
                    }
            }
        }
        leg_level(2, 2.f / 3.f, pB, pA);   // P3
        leg_level(3, 3.f / 4.f, pA, pB);   // P4
        leg_level(4, 4.f / 5.f, pB, pA);   // P5
        leg_level(5, 5.f / 6.f, pA, pB);   // P6 = pB

        // ---------------- epilogue: out = P6 @ C^T + beta --------------------
        #pragma unroll
        for (int u = 0; u < 2; ++u)
            #pragma unroll
            for (int t = 0; t < 2; ++t) {
                // transpose P6 (C/D layout) -> A-op layout, two k-32 phases
                // through a 16x32 XOR-swizzled per-wave scratch
                s16x8 p6h[2], p6l[2];
                #pragma unroll
                for (int s = 0; s < 2; ++s) {
                    #pragma unroll
                    for (int f_ = 0; f_ < 2; ++f_) {
                        const int f    = 2 * s + f_;
                        const int colp = (f_ << 4) + lrow;
                        #pragma unroll
                        for (int r = 0; r < 4; ++r) {
                            const int row = lhi * 4 + r;
                            const int g4  = ((colp >> 2) ^ row) & 7;
                            scr[row * 32 + g4 * 4 + (colp & 3)] = pB[u][t][f][r];
                        }
                    }
                    float vv[8];
                    #pragma unroll
                    for (int jg = 0; jg < 2; ++jg) {
                        const int g4r = (((lhi << 1) + jg) ^ lrow) & 7;
                        const float4 q = *(const float4*)(scr + lrow * 32 + g4r * 4);
                        vv[jg * 4 + 0] = q.x; vv[jg * 4 + 1] = q.y;
                        vv[jg * 4 + 2] = q.z; vv[jg * 4 + 3] = q.w;
                    }
                    #pragma unroll
                    for (int j = 0; j < 8; ++j) {
                        const unsigned short h = f2bf(vv[j]);
                        const float hf = __builtin_bit_cast(float, (unsigned)h << 16);
                        p6h[s][j] = (short)h;
                        p6l[s][j] = (short)f2bf(vv[j] - hf);
                    }
                }
                #pragma unroll
                for (int fo = 0; fo < 2; ++fo) {
                    const s16x8 ch0 = *(const s16x8*)(smem + CF_OFF + ((0 << 1) + fo) * 1024 + lane * 16);
                    const s16x8 ch1 = *(const s16x8*)(smem + CF_OFF + ((1 << 1) + fo) * 1024 + lane * 16);
                    const s16x8 cl0 = *(const s16x8*)(smem + CF_OFF + ((2 << 1) + fo) * 1024 + lane * 16);
                    const s16x8 cl1 = *(const s16x8*)(smem + CF_OFF + ((3 << 1) + fo) * 1024 + lane * 16);
                    f32x4 o = {0.f, 0.f, 0.f, 0.f};
                    o = __builtin_amdgcn_mfma_f32_16x16x32_bf16(p6h[0], ch0, o, 0, 0, 0);
                    o = __builtin_amdgcn_mfma_f32_16x16x32_bf16(p6l[0], ch0, o, 0, 0, 0);
                    o = __builtin_amdgcn_mfma_f32_16x16x32_bf16(p6h[0], cl0, o, 0, 0, 0);
                    o = __builtin_amdgcn_mfma_f32_16x16x32_bf16(p6h[1], ch1, o, 0, 0, 0);
                    o = __builtin_amdgcn_mfma_f32_16x16x32_bf16(p6l[1], ch1, o, 0, 0, 0);
                    o = __builtin_amdgcn_mfma_f32_16x16x32_bf16(p6h[1], cl1, o, 0, 0, 0);
                    const float bb = fo ? beta1 : beta0;
                    const size_t r0 = rowbase + (size_t)it * 64 + u * 32 + t * 16 + lhi * 4;
                    #pragma unroll
                    for (int r = 0; r < 4; ++r)
                        out[(r0 + r) * 32 + (fo << 4) + lrow] = o[r] + bb;
                }
            }
    }
}

extern "C" void kernel_launch(void* const* d_in, const int* in_sizes, int n_in,
                              void* d_out, int out_size, void* d_ws, size_t ws_size,
                              hipStream_t stream) {
    const float* z    = (const float*)d_in[0];
    const float* T    = (const float*)d_in[1];
    const float* C    = (const float*)d_in[2];
    const float* beta = (const float*)d_in[3];
    float* out = (float*)d_out;
    (void)in_sizes; (void)n_in; (void)out_size; (void)ws_size;

    char* ws = (char*)d_ws;              // needs WS_TOTAL = 104 KB

    leg_prep<<<1, 512, 0, stream>>>(T, C, ws);

    hipFuncSetAttribute((const void*)leg_mfma,
                        hipFuncAttributeMaxDynamicSharedMemorySize, SMEM_BYTES);
    leg_mfma<<<BLOCKS, THREADS, SMEM_BYTES, stream>>>(z, ws, beta, out);
}